// Round 2
// baseline (342.577 us; speedup 1.0000x reference)
//
#include <hip/hip_runtime.h>
#include <hip/hip_bf16.h>
#include <stdint.h>

#define NEG_INF -100000000.0f

typedef __attribute__((ext_vector_type(8))) short bf16x8;
typedef __attribute__((ext_vector_type(4))) float f32x4;

static __device__ __forceinline__ short f2bf(float x) {
    unsigned u = __float_as_uint(x);
    u = u + 0x7FFFu + ((u >> 16) & 1u);
    return (short)(u >> 16);
}

// ---------------- kernel 1: transpose + bf16-convert weights ----------------
// w [256 k][256 c] f32  ->  wt [256 c][256 k] bf16
// w_query additionally scaled by 1/16 (= 1/sqrt(D), exact in bf16).
__global__ void wtrans_kernel(const float* __restrict__ wq, const float* __restrict__ wk,
                              short* __restrict__ wtq, short* __restrict__ wtk) {
    __shared__ float tile[32][33];
    const float* w = blockIdx.z ? wk : wq;
    short* wt = blockIdx.z ? wtk : wtq;
    float scale = blockIdx.z ? 1.0f : 0.0625f;
    int tx = threadIdx.x, ty = threadIdx.y;
    int c0 = blockIdx.x * 32;   // col block of w
    int k0 = blockIdx.y * 32;   // row block of w
#pragma unroll
    for (int i = 0; i < 4; i++)
        tile[ty + i * 8][tx] = w[(k0 + ty + i * 8) * 256 + c0 + tx];
    __syncthreads();
#pragma unroll
    for (int i = 0; i < 4; i++)
        wt[(c0 + ty + i * 8) * 256 + k0 + tx] = f2bf(tile[tx][ty + i * 8] * scale);
}

// ---------------- kernel 2: projection GEMM  X[65536,256] @ W[256,256] -> bf16 ----------------
// blockIdx.y: 0 -> Q = q @ wq' ; 1 -> K = k @ wk
// Output layout is MFMA-fragment swizzled: [b 64][dc 8][row 1024][ks 32] bf16,
// i.e. element (global_row, col) lands at (((row>>10)*8 + (col>>5))*1024 + (row&1023))*32 + (col&31)
__global__ __launch_bounds__(512, 4)
void proj_kernel(const float* __restrict__ qin, const float* __restrict__ kin,
                 const short* __restrict__ wtq, const short* __restrict__ wtk,
                 short* __restrict__ Qb, short* __restrict__ Kb) {
    const float* x  = blockIdx.y ? kin : qin;
    const short* wt = blockIdx.y ? wtk : wtq;   // [c 256][k 256] bf16
    short* outp     = blockIdx.y ? Kb  : Qb;

    __shared__ __align__(16) short xlds[64 * 32];    // [row][32 k], 64B row stride
    __shared__ __align__(16) short wlds[256 * 32];   // [c][32 k],  64B row stride

    int t = threadIdx.x;
    int lane = t & 63, w = t >> 6;
    int l15 = lane & 15, g = lane >> 4;
    int rowbase = blockIdx.x * 64;

    f32x4 zero = {0.f, 0.f, 0.f, 0.f};
    f32x4 acc[4][2];
#pragma unroll
    for (int m = 0; m < 4; m++)
#pragma unroll
        for (int n = 0; n < 2; n++) acc[m][n] = zero;

    for (int dc = 0; dc < 8; dc++) {
        __syncthreads();
        // stage X chunk [64 rows][32 k] f32 -> bf16
        {
            int row = t >> 3, seg = t & 7;
            float4 v = *reinterpret_cast<const float4*>(x + (size_t)(rowbase + row) * 256 + dc * 32 + seg * 4);
            short4 bb;
            bb.x = f2bf(v.x); bb.y = f2bf(v.y); bb.z = f2bf(v.z); bb.w = f2bf(v.w);
            *reinterpret_cast<short4*>(&xlds[row * 32 + seg * 4]) = bb;
        }
        // stage W^T chunk [256 c][32 k] bf16
#pragma unroll
        for (int i = 0; i < 2; i++) {
            int idx = i * 512 + t;
            int c = idx >> 2, seg = idx & 3;
            int4 v = *reinterpret_cast<const int4*>(wt + c * 256 + dc * 32 + seg * 8);
            *reinterpret_cast<int4*>(&wlds[idx * 8]) = v;
        }
        __syncthreads();

        bf16x8 a[4], bfr[2];
#pragma unroll
        for (int m = 0; m < 4; m++)
            a[m] = *reinterpret_cast<const bf16x8*>(&xlds[(m * 16 + l15) * 32 + g * 8]);
#pragma unroll
        for (int n = 0; n < 2; n++) {
            int c = w * 32 + n * 16 + l15;
            bfr[n] = *reinterpret_cast<const bf16x8*>(&wlds[c * 32 + g * 8]);
        }
#pragma unroll
        for (int m = 0; m < 4; m++)
#pragma unroll
            for (int n = 0; n < 2; n++)
                acc[m][n] = __builtin_amdgcn_mfma_f32_16x16x32_bf16(a[m], bfr[n], acc[m][n], 0, 0, 0);
    }

    // write out bf16 to swizzled layout
#pragma unroll
    for (int m = 0; m < 4; m++)
#pragma unroll
        for (int n = 0; n < 2; n++) {
            int col = w * 32 + n * 16 + l15;
            int dcc = col >> 5, ks = col & 31;
#pragma unroll
            for (int r = 0; r < 4; r++) {
                int row = rowbase + m * 16 + g * 4 + r;
                size_t idx = (((size_t)(row >> 10) * 8 + dcc) * 1024 + (row & 1023)) * 32 + ks;
                outp[idx] = f2bf(acc[m][n][r]);
            }
        }
}

// ---------------- kernel 3: fused QK^T + tanh-clip + mask + log_softmax ----------------
// block: 32 q-rows x 1024 k-cols, 8 waves (wave w owns cols w*128..+128).
// Q,K read directly from global in fragment-swizzled layout -> no LDS staging,
// no barriers in the main loop.
__global__ __launch_bounds__(512, 4)
void attn_kernel(const short* __restrict__ Qs, const short* __restrict__ Ks,
                 const int* __restrict__ mask, float* __restrict__ out) {
    __shared__ float redbuf[8 * 32];
    __shared__ float lsebuf[32];

    int t = threadIdx.x;
    int lane = t & 63, w = t >> 6;
    int l15 = lane & 15, g = lane >> 4;

    // XCD swizzle: 2048 blocks, 8 XCDs -> each XCD gets 256 consecutive wgs
    // = 8 whole batches (K working set 4MB = one XCD L2).
    int bid = blockIdx.x;
    int wg = (bid & 7) * 256 + (bid >> 3);
    int b = wg >> 5;
    int brow = (wg & 31) * 32;

    const short* qb = Qs + (size_t)b * 8 * 1024 * 32;
    const short* kb = Ks + (size_t)b * 8 * 1024 * 32;

    f32x4 zero = {0.f, 0.f, 0.f, 0.f};
    f32x4 acc[2][8];
#pragma unroll
    for (int m = 0; m < 2; m++)
#pragma unroll
        for (int n = 0; n < 8; n++) acc[m][n] = zero;

    for (int dc = 0; dc < 8; dc++) {
        const short* qc = qb + (size_t)dc * 1024 * 32;
        const short* kc = kb + (size_t)dc * 1024 * 32;
        bf16x8 a0 = *reinterpret_cast<const bf16x8*>(qc + (brow + l15) * 32 + g * 8);
        bf16x8 a1 = *reinterpret_cast<const bf16x8*>(qc + (brow + 16 + l15) * 32 + g * 8);
#pragma unroll
        for (int n = 0; n < 8; n++) {
            bf16x8 bf = *reinterpret_cast<const bf16x8*>(kc + (w * 128 + n * 16 + l15) * 32 + g * 8);
            acc[0][n] = __builtin_amdgcn_mfma_f32_16x16x32_bf16(a0, bf, acc[0][n], 0, 0, 0);
            acc[1][n] = __builtin_amdgcn_mfma_f32_16x16x32_bf16(a1, bf, acc[1][n], 0, 0, 0);
        }
    }

    // epilogue: u already includes 1/16 norm (folded into wq).
    // uc = 10*tanh(u); mask==1 -> NEG_INF; rowsum of exp(uc)
    float rowsum[2][4];
#pragma unroll
    for (int m = 0; m < 2; m++)
#pragma unroll
        for (int r = 0; r < 4; r++) rowsum[m][r] = 0.f;

#pragma unroll
    for (int m = 0; m < 2; m++)
#pragma unroll
        for (int n = 0; n < 8; n++) {
            const int* mrow = mask + ((size_t)b * 1024 + brow + m * 16 + g * 4) * 1024
                              + w * 128 + n * 16 + l15;
#pragma unroll
            for (int r = 0; r < 4; r++) {
                float un = acc[m][n][r];
                float e2 = __expf(2.0f * un);
                float uc = 10.0f - 20.0f / (e2 + 1.0f);   // 10*tanh(un)
                int mv = mrow[(size_t)r * 1024];
                bool msk = (mv == 1);
                acc[m][n][r] = msk ? NEG_INF : uc;
                rowsum[m][r] += msk ? 0.0f : __expf(uc);
            }
        }

    // reduce across the 16 lanes sharing a row
#pragma unroll
    for (int m = 0; m < 2; m++)
#pragma unroll
        for (int r = 0; r < 4; r++) {
            float s = rowsum[m][r];
            s += __shfl_xor(s, 1);
            s += __shfl_xor(s, 2);
            s += __shfl_xor(s, 4);
            s += __shfl_xor(s, 8);
            rowsum[m][r] = s;
        }
    if (l15 == 0) {
#pragma unroll
        for (int m = 0; m < 2; m++)
#pragma unroll
            for (int r = 0; r < 4; r++)
                redbuf[w * 32 + m * 16 + g * 4 + r] = rowsum[m][r];
    }
    __syncthreads();
    if (t < 32) {
        float s = 0.f;
#pragma unroll
        for (int ww = 0; ww < 8; ww++) s += redbuf[ww * 32 + t];
        lsebuf[t] = __logf(fmaxf(s, 1e-30f));
    }
    __syncthreads();

    // write output: out = u - lse
    float* obase = out + ((size_t)b * 1024 + brow) * 1024;
#pragma unroll
    for (int m = 0; m < 2; m++)
#pragma unroll
        for (int r = 0; r < 4; r++) {
            int row_l = m * 16 + g * 4 + r;
            float lse = lsebuf[row_l];
#pragma unroll
            for (int n = 0; n < 8; n++) {
                int col = w * 128 + n * 16 + l15;
                obase[(size_t)row_l * 1024 + col] = acc[m][n][r] - lse;
            }
        }
}

extern "C" void kernel_launch(void* const* d_in, const int* in_sizes, int n_in,
                              void* d_out, int out_size, void* d_ws, size_t ws_size,
                              hipStream_t stream) {
    const float* q  = (const float*)d_in[0];
    const float* k  = (const float*)d_in[1];
    const float* wq = (const float*)d_in[2];
    const float* wk = (const float*)d_in[3];
    const int* mask = (const int*)d_in[4];
    float* out = (float*)d_out;

    char* ws = (char*)d_ws;
    short* wtq = (short*)ws;                                  // 128KB
    short* wtk = (short*)(ws + 131072);                       // 128KB
    short* Qb  = (short*)(ws + 262144);                       // 32MB
    short* Kb  = (short*)(ws + 262144 + 33554432);            // 32MB

    wtrans_kernel<<<dim3(8, 8, 2), dim3(32, 8), 0, stream>>>(wq, wk, wtq, wtk);
    proj_kernel<<<dim3(1024, 2), 512, 0, stream>>>(q, k, wtq, wtk, Qb, Kb);
    attn_kernel<<<dim3(2048), 512, 0, stream>>>(Qb, Kb, mask, out);
}

// Round 3
// 274.554 us; speedup vs baseline: 1.2478x; 1.2478x over previous
//
#include <hip/hip_runtime.h>
#include <hip/hip_bf16.h>
#include <stdint.h>

#define NEG_INF -100000000.0f

typedef __attribute__((ext_vector_type(8))) short bf16x8;
typedef __attribute__((ext_vector_type(4))) float f32x4;

static __device__ __forceinline__ short f2bf(float x) {
    unsigned u = __float_as_uint(x);
    u = u + 0x7FFFu + ((u >> 16) & 1u);
    return (short)(u >> 16);
}

// ---------------- kernel 1: transpose + bf16-convert weights ----------------
// w [256 k][256 c] f32  ->  wt [256 c][256 k] bf16
// w_query additionally scaled by 1/16 (= 1/sqrt(D), exact in bf16).
__global__ void wtrans_kernel(const float* __restrict__ wq, const float* __restrict__ wk,
                              short* __restrict__ wtq, short* __restrict__ wtk) {
    __shared__ float tile[32][33];
    const float* w = blockIdx.z ? wk : wq;
    short* wt = blockIdx.z ? wtk : wtq;
    float scale = blockIdx.z ? 1.0f : 0.0625f;
    int tx = threadIdx.x, ty = threadIdx.y;
    int c0 = blockIdx.x * 32;   // col block of w
    int k0 = blockIdx.y * 32;   // row block of w
#pragma unroll
    for (int i = 0; i < 4; i++)
        tile[ty + i * 8][tx] = w[(k0 + ty + i * 8) * 256 + c0 + tx];
    __syncthreads();
#pragma unroll
    for (int i = 0; i < 4; i++)
        wt[(c0 + ty + i * 8) * 256 + k0 + tx] = f2bf(tile[tx][ty + i * 8] * scale);
}

// ---------------- kernel 2: projection GEMM  X[65536,256] @ W[256,256] -> bf16 ----------------
// blockIdx.y: 0 -> Q = q @ wq' ; 1 -> K = k @ wk
// Output layout is MFMA-fragment swizzled: [b 64][dc 8][row 1024][ks 32] bf16
__global__ __launch_bounds__(512, 4)
void proj_kernel(const float* __restrict__ qin, const float* __restrict__ kin,
                 const short* __restrict__ wtq, const short* __restrict__ wtk,
                 short* __restrict__ Qb, short* __restrict__ Kb) {
    const float* x  = blockIdx.y ? kin : qin;
    const short* wt = blockIdx.y ? wtk : wtq;   // [c 256][k 256] bf16
    short* outp     = blockIdx.y ? Kb  : Qb;

    __shared__ __align__(16) short xlds[64 * 32];    // [row][32 k]
    __shared__ __align__(16) short wlds[256 * 32];   // [c][32 k]

    int t = threadIdx.x;
    int lane = t & 63, w = t >> 6;
    int l15 = lane & 15, g = lane >> 4;
    int rowbase = blockIdx.x * 64;

    f32x4 zero = {0.f, 0.f, 0.f, 0.f};
    f32x4 acc[4][2];
#pragma unroll
    for (int m = 0; m < 4; m++)
#pragma unroll
        for (int n = 0; n < 2; n++) acc[m][n] = zero;

    for (int dc = 0; dc < 8; dc++) {
        __syncthreads();
        {
            int row = t >> 3, seg = t & 7;
            float4 v = *reinterpret_cast<const float4*>(x + (size_t)(rowbase + row) * 256 + dc * 32 + seg * 4);
            short4 bb;
            bb.x = f2bf(v.x); bb.y = f2bf(v.y); bb.z = f2bf(v.z); bb.w = f2bf(v.w);
            *reinterpret_cast<short4*>(&xlds[row * 32 + seg * 4]) = bb;
        }
#pragma unroll
        for (int i = 0; i < 2; i++) {
            int idx = i * 512 + t;
            int c = idx >> 2, seg = idx & 3;
            int4 v = *reinterpret_cast<const int4*>(wt + c * 256 + dc * 32 + seg * 8);
            *reinterpret_cast<int4*>(&wlds[idx * 8]) = v;
        }
        __syncthreads();

        bf16x8 a[4], bfr[2];
#pragma unroll
        for (int m = 0; m < 4; m++)
            a[m] = *reinterpret_cast<const bf16x8*>(&xlds[(m * 16 + l15) * 32 + g * 8]);
#pragma unroll
        for (int n = 0; n < 2; n++) {
            int c = w * 32 + n * 16 + l15;
            bfr[n] = *reinterpret_cast<const bf16x8*>(&wlds[c * 32 + g * 8]);
        }
#pragma unroll
        for (int m = 0; m < 4; m++)
#pragma unroll
            for (int n = 0; n < 2; n++)
                acc[m][n] = __builtin_amdgcn_mfma_f32_16x16x32_bf16(a[m], bfr[n], acc[m][n], 0, 0, 0);
    }

#pragma unroll
    for (int m = 0; m < 4; m++)
#pragma unroll
        for (int n = 0; n < 2; n++) {
            int col = w * 32 + n * 16 + l15;
            int dcc = col >> 5, ks = col & 31;
#pragma unroll
            for (int r = 0; r < 4; r++) {
                int row = rowbase + m * 16 + g * 4 + r;
                size_t idx = (((size_t)(row >> 10) * 8 + dcc) * 1024 + (row & 1023)) * 32 + ks;
                outp[idx] = f2bf(acc[m][n][r]);
            }
        }
}

// ---------------- kernel 3: fused QK^T + tanh-clip + mask + log_softmax ----------------
// Phase A: 32 q-rows x 1024 cols QK^T per block, fragment-direct global loads.
// Phase B: per 16-row half, dump U to LDS in fragment order, re-read row-major:
// each wave owns 2 full rows -> mask/out traffic is long sequential int4/float4
// streams; row reduction stays inside one 32-lane half (no cross-wave reduce).
__global__ __launch_bounds__(512, 4)
void attn_kernel(const short* __restrict__ Qs, const short* __restrict__ Ks,
                 const int* __restrict__ mask, float* __restrict__ out) {
    __shared__ __align__(16) float ulds[16 * 1024];   // 64KB -> 2 blocks/CU

    int t = threadIdx.x;
    int lane = t & 63, w = t >> 6;
    int l15 = lane & 15, g = lane >> 4;

    // XCD swizzle: each XCD gets 256 consecutive wgs = 8 whole batches.
    int bid = blockIdx.x;
    int wg = (bid & 7) * 256 + (bid >> 3);
    int b = wg >> 5;
    int brow = (wg & 31) * 32;

    const short* qb = Qs + (size_t)b * 8 * 1024 * 32;
    const short* kb = Ks + (size_t)b * 8 * 1024 * 32;

    f32x4 zero = {0.f, 0.f, 0.f, 0.f};
    f32x4 acc[2][8];
#pragma unroll
    for (int m = 0; m < 2; m++)
#pragma unroll
        for (int n = 0; n < 8; n++) acc[m][n] = zero;

    for (int dc = 0; dc < 8; dc++) {
        const short* qc = qb + (size_t)dc * 1024 * 32;
        const short* kc = kb + (size_t)dc * 1024 * 32;
        bf16x8 a0 = *reinterpret_cast<const bf16x8*>(qc + (brow + l15) * 32 + g * 8);
        bf16x8 a1 = *reinterpret_cast<const bf16x8*>(qc + (brow + 16 + l15) * 32 + g * 8);
#pragma unroll
        for (int n = 0; n < 8; n++) {
            bf16x8 bf = *reinterpret_cast<const bf16x8*>(kc + (w * 128 + n * 16 + l15) * 32 + g * 8);
            acc[0][n] = __builtin_amdgcn_mfma_f32_16x16x32_bf16(a0, bf, acc[0][n], 0, 0, 0);
            acc[1][n] = __builtin_amdgcn_mfma_f32_16x16x32_bf16(a1, bf, acc[1][n], 0, 0, 0);
        }
    }

    int row = t >> 5;          // 0..15 within half-tile
    int j = t & 31;            // 32 col-chunks of 4 floats
    float* urow = ulds + row * 1024;

#pragma unroll
    for (int m = 0; m < 2; m++) {
        __syncthreads();   // previous half's LDS reads done (no-op cost first iter)
        // dump fragments -> LDS row-major U[16][1024]
#pragma unroll
        for (int n = 0; n < 8; n++)
#pragma unroll
            for (int r = 0; r < 4; r++)
                ulds[(g * 4 + r) * 1024 + w * 128 + n * 16 + l15] = acc[m][n][r];
        __syncthreads();

        const int* mrow = mask + ((size_t)b * 1024 + brow + m * 16 + row) * 1024;
        float* orow = out + ((size_t)b * 1024 + brow + m * 16 + row) * 1024;

        float psum = 0.f;
#pragma unroll
        for (int i = 0; i < 8; i++) {
            int col = j * 4 + i * 128;
            int4 mv = *reinterpret_cast<const int4*>(mrow + col);
            float4 u4 = *reinterpret_cast<const float4*>(urow + col);
            float uc[4];
            int mvv[4] = {mv.x, mv.y, mv.z, mv.w};
            float uv[4] = {u4.x, u4.y, u4.z, u4.w};
#pragma unroll
            for (int c = 0; c < 4; c++) {
                float e2 = __expf(2.0f * uv[c]);
                float tc = 10.0f - 20.0f / (e2 + 1.0f);    // 10*tanh(u)
                bool msk = (mvv[c] == 1);
                uc[c] = msk ? NEG_INF : tc;
                psum += msk ? 0.0f : __expf(tc);
            }
            float4 s = {uc[0], uc[1], uc[2], uc[3]};
            *reinterpret_cast<float4*>(urow + col) = s;    // park uc back in LDS
        }

        // reduce across the 32 lanes sharing this row (xor<=16 stays in half)
        psum += __shfl_xor(psum, 1);
        psum += __shfl_xor(psum, 2);
        psum += __shfl_xor(psum, 4);
        psum += __shfl_xor(psum, 8);
        psum += __shfl_xor(psum, 16);
        float lse = __logf(fmaxf(psum, 1e-30f));

#pragma unroll
        for (int i = 0; i < 8; i++) {
            int col = j * 4 + i * 128;
            float4 u4 = *reinterpret_cast<const float4*>(urow + col);
            float4 o = {u4.x - lse, u4.y - lse, u4.z - lse, u4.w - lse};
            *reinterpret_cast<float4*>(orow + col) = o;
        }
    }
}

extern "C" void kernel_launch(void* const* d_in, const int* in_sizes, int n_in,
                              void* d_out, int out_size, void* d_ws, size_t ws_size,
                              hipStream_t stream) {
    const float* q  = (const float*)d_in[0];
    const float* k  = (const float*)d_in[1];
    const float* wq = (const float*)d_in[2];
    const float* wk = (const float*)d_in[3];
    const int* mask = (const int*)d_in[4];
    float* out = (float*)d_out;

    char* ws = (char*)d_ws;
    short* wtq = (short*)ws;                                  // 128KB
    short* wtk = (short*)(ws + 131072);                       // 128KB
    short* Qb  = (short*)(ws + 262144);                       // 32MB
    short* Kb  = (short*)(ws + 262144 + 33554432);            // 32MB

    wtrans_kernel<<<dim3(8, 8, 2), dim3(32, 8), 0, stream>>>(wq, wk, wtq, wtk);
    proj_kernel<<<dim3(1024, 2), 512, 0, stream>>>(q, k, wtq, wtk, Qb, Kb);
    attn_kernel<<<dim3(2048), 512, 0, stream>>>(Qb, Kb, mask, out);
}